// Round 17
// baseline (160.766 us; speedup 1.0000x reference)
//
#include <hip/hip_runtime.h>
#include <cstdint>
#include <cstddef>

#define NND 100000
#define NED 640000
#define NSCAN_B 98          // ceil(NND/1024)
#define NPART 8             // dst-space partitions
#define PSZ 12500           // NND / NPART  (LDS histogram bins per partition)
#define KCH 25              // edge chunks
#define CHE 25600           // edges per chunk (25600*25 = 640,000 exact)
#define HISTB (NPART * KCH)             // 200 hist/fill blocks
#define CVTX_B 782          // cvt_x blocks: ceil(3,200,000 float4 / 4096)
#define CVTW_B 48           // cvt_w blocks: 49,152 / 1024 exact
#define PRE_N (HISTB + CVTX_B + CVTW_B) // 1030 pre_all blocks (1024 thr)

typedef unsigned int u32;
typedef unsigned short u16;
typedef __attribute__((ext_vector_type(8))) short bf16x8;
typedef __attribute__((ext_vector_type(4))) float f32x4;
typedef __attribute__((ext_vector_type(2))) u32 u32x2;
typedef __attribute__((ext_vector_type(4))) u32 u32x4;

// ---------------------------------------------------------------------------
// helpers: fp32 <-> bf16 (RNE)
// ---------------------------------------------------------------------------
__device__ __forceinline__ u16 f2b(float f) {
    u32 u = __float_as_uint(f);
    return (u16)((u + 0x7fffu + ((u >> 16) & 1u)) >> 16);
}
__device__ __forceinline__ float b2f(u16 b) {
    return __uint_as_float(((u32)b) << 16);
}
__device__ __forceinline__ u32 pack2(float a, float b) {
    return (u32)f2b(a) | ((u32)f2b(b) << 16);
}

// ---------------------------------------------------------------------------
// pre_all — ZERO global atomics, 1024-thread blocks:
//   blocks [0, 200):      pass A — LDS count histogram per (partition, chunk)
//   blocks [200, 982):    cvt x->bf16
//   blocks [982, 1030):   cvt W1,W2 -> transposed bf16
// ---------------------------------------------------------------------------
__global__ __launch_bounds__(1024)
void pre_all(const int* __restrict__ ei, int* __restrict__ cntmat,
             const float* __restrict__ x, u32* __restrict__ xb,
             const float* __restrict__ W1, const float* __restrict__ W2,
             u16* __restrict__ W1t, u16* __restrict__ W2t) {
    __shared__ int hist[PSZ];
    const int b = blockIdx.x;
    const int t = threadIdx.x;
    if (b < HISTB) {
        const int part = b & 7, chunk = b >> 3;
        const int lo = part * PSZ;
        for (int i = t; i < PSZ; i += 1024) hist[i] = 0;
        __syncthreads();
        const int base = chunk * CHE;
        #pragma unroll
        for (int it = 0; it < 7; ++it) {
            const int off = (it * 1024 + t) * 4;
            if (off < CHE) {
                const int4 d = *(const int4*)&ei[NED + base + off];
                const int dv[4] = {d.x, d.y, d.z, d.w};
                #pragma unroll
                for (int j = 0; j < 4; ++j) {
                    const unsigned u = (unsigned)(dv[j] - lo);
                    if (u < PSZ) atomicAdd(&hist[u], 1);
                }
            }
        }
        __syncthreads();
        for (int i = t; i < PSZ; i += 1024)
            cntmat[chunk * NND + lo + i] = hist[i];
    } else if (b < HISTB + CVTX_B) {
        const int cb = b - HISTB;
        const float4* __restrict__ x4 = (const float4*)x;
        #pragma unroll
        for (int j = 0; j < 4; ++j) {
            const int f4 = cb * 4096 + j * 1024 + t;      // float4 index
            if (f4 < 3200000) {
                const float4 v = x4[f4];
                xb[(size_t)f4 * 2 + 0] = pack2(v.x, v.y);
                xb[(size_t)f4 * 2 + 1] = pack2(v.z, v.w);
            }
        }
    } else {
        const int i = (b - (HISTB + CVTX_B)) * 1024 + t;  // < 49,152 exact
        if (i < 128 * 256) {
            const int k = i >> 8, n = i & 255;
            W1t[n * 128 + k] = f2b(W1[i]);
        } else {
            const int j = i - 128 * 256;                  // j < 256*64
            const int k = j >> 6, n = j & 63;
            W2t[n * 256 + k] = f2b(W2[j]);
        }
    }
}

// ---------------------------------------------------------------------------
// scanA_dinv: per bin, (1) scan cntmat over the 25 chunks IN PLACE, (2)
// dinv = rsqrt(1+deg), (3) per-1024 exclusive scan of deg -> offs + bsum.
// ---------------------------------------------------------------------------
__global__ __launch_bounds__(256)
void scanA_dinv(int* __restrict__ cntmat, int* __restrict__ offs,
                int* __restrict__ bsum, float* __restrict__ dinv) {
    __shared__ int s[256];
    const int t = threadIdx.x;
    const int base = blockIdx.x * 1024 + t * 4;
    int t0 = 0, t1 = 0, t2 = 0, t3 = 0;
    if (base < NND) {
        #pragma unroll 5
        for (int c = 0; c < KCH; ++c) {
            int4* p = (int4*)&cntmat[c * NND + base];
            const int4 v = *p;
            *p = make_int4(t0, t1, t2, t3);               // exclusive base
            t0 += v.x; t1 += v.y; t2 += v.z; t3 += v.w;
        }
        dinv[base + 0] = rsqrtf(1.0f + (float)t0);
        dinv[base + 1] = rsqrtf(1.0f + (float)t1);
        dinv[base + 2] = rsqrtf(1.0f + (float)t2);
        dinv[base + 3] = rsqrtf(1.0f + (float)t3);
    }
    const int local = t0 + t1 + t2 + t3;
    s[t] = local;
    __syncthreads();
    for (int off = 1; off < 256; off <<= 1) {
        int v = (t >= off) ? s[t - off] : 0;
        __syncthreads();
        s[t] += v;
        __syncthreads();
    }
    const int excl = s[t] - local;
    if (t == 255) bsum[blockIdx.x] = s[255];
    if (base < NND) {
        offs[base + 0] = excl;
        offs[base + 1] = excl + t0;
        offs[base + 2] = excl + t0 + t1;
        offs[base + 3] = excl + t0 + t1 + t2;
    }
}

// scanC2: each block redundantly prefixes the 98 block sums, then applies.
__global__ __launch_bounds__(256)
void scanC2(int* __restrict__ offs, const int* __restrict__ bsum) {
    __shared__ int pref[NSCAN_B];
    if (threadIdx.x < NSCAN_B) pref[threadIdx.x] = bsum[threadIdx.x];
    __syncthreads();
    if (threadIdx.x == 0) {
        int run = 0;
        #pragma unroll 1
        for (int b = 0; b < NSCAN_B; ++b) { int v = pref[b]; pref[b] = run; run += v; }
    }
    __syncthreads();
    const int i = blockIdx.x * 256 + threadIdx.x;
    if (i < NND) offs[i] += pref[i >> 10];
    if (i == 0) offs[NND] = NED;
}

// ---------------------------------------------------------------------------
// fill_lds: LDS-cursor CSR fill, zero global atomics, 1024-thread blocks.
// ---------------------------------------------------------------------------
__global__ __launch_bounds__(1024)
void fill_lds(const int* __restrict__ ei, const int* __restrict__ cntmat,
              const int* __restrict__ offs, const float* __restrict__ dinv,
              u32x2* __restrict__ recS) {
    __shared__ int cur[PSZ];
    const int t = threadIdx.x;
    const int part = blockIdx.x & 7, chunk = blockIdx.x >> 3;
    const int lo = part * PSZ;
    for (int i = t; i < PSZ; i += 1024)
        cur[i] = offs[lo + i] + cntmat[chunk * NND + lo + i];
    __syncthreads();
    const int base = chunk * CHE;
    #pragma unroll
    for (int it = 0; it < 7; ++it) {
        const int off = (it * 1024 + t) * 4;
        if (off < CHE) {
            const int e = base + off;
            const int4 s4 = *(const int4*)&ei[e];
            const int4 d4 = *(const int4*)&ei[NED + e];
            const int sv[4] = {s4.x, s4.y, s4.z, s4.w};
            const int dv[4] = {d4.x, d4.y, d4.z, d4.w};
            #pragma unroll
            for (int j = 0; j < 4; ++j) {
                const unsigned u = (unsigned)(dv[j] - lo);
                if (u < PSZ) {
                    const float wt = dinv[sv[j]] * dinv[dv[j]];
                    const int pos = atomicAdd(&cur[u], 1);
                    u32x2 rec = {(u32)sv[j], __float_as_uint(wt)};
                    recS[pos] = rec;
                }
            }
        }
    }
}

// ---------------------------------------------------------------------------
// CSR gather (bf16), 8-wide predicated edge groups, packed edge records.
// FOUR nodes per wave: 16 lanes x u32x4 (16B) = 256B row.
// z[d] = dinv[d]^2*x[d] + sum_e wt[e]*x[src[e]]
// ---------------------------------------------------------------------------
__global__ __launch_bounds__(256)
void gather128b(const int* __restrict__ offs, const u32x2* __restrict__ recS,
                const float* __restrict__ dinv,
                const u32x4* __restrict__ xb4, u32x4* __restrict__ zb4) {
    const int t    = blockIdx.x * 256 + threadIdx.x;
    const int d    = t >> 4;
    const int lane = t & 15;
    if (d >= NND) return;
    const int beg = offs[d], end = offs[d + 1];
    const float dd = dinv[d];
    const u32x4 s = xb4[(size_t)d * 16 + lane];
    const float d2 = dd * dd;
    float a0 = b2f((u16)s.x) * d2, a1 = b2f((u16)(s.x >> 16)) * d2;
    float a2 = b2f((u16)s.y) * d2, a3 = b2f((u16)(s.y >> 16)) * d2;
    float a4 = b2f((u16)s.z) * d2, a5 = b2f((u16)(s.z >> 16)) * d2;
    float a6 = b2f((u16)s.w) * d2, a7 = b2f((u16)(s.w >> 16)) * d2;
    for (int e = beg; e < end; e += 8) {
        u32x2 r[8]; float wi[8]; u32x4 vi[8];
        #pragma unroll
        for (int j = 0; j < 8; ++j) {
            const int ee = e + j;
            r[j] = __builtin_nontemporal_load(&recS[(ee < end) ? ee : (end - 1)]);
        }
        #pragma unroll
        for (int j = 0; j < 8; ++j) {
            wi[j] = (e + j < end) ? __uint_as_float(r[j].y) : 0.0f;
            vi[j] = xb4[(size_t)r[j].x * 16 + lane];
        }
        #pragma unroll
        for (int j = 0; j < 8; ++j) {
            a0 = fmaf(wi[j], b2f((u16)vi[j].x), a0);
            a1 = fmaf(wi[j], b2f((u16)(vi[j].x >> 16)), a1);
            a2 = fmaf(wi[j], b2f((u16)vi[j].y), a2);
            a3 = fmaf(wi[j], b2f((u16)(vi[j].y >> 16)), a3);
            a4 = fmaf(wi[j], b2f((u16)vi[j].z), a4);
            a5 = fmaf(wi[j], b2f((u16)(vi[j].z >> 16)), a5);
            a6 = fmaf(wi[j], b2f((u16)vi[j].w), a6);
            a7 = fmaf(wi[j], b2f((u16)(vi[j].w >> 16)), a7);
        }
    }
    u32x4 o = {pack2(a0, a1), pack2(a2, a3), pack2(a4, a5), pack2(a6, a7)};
    zb4[(size_t)d * 16 + lane] = o;
}

// out[d] = b2 + dinv[d]^2*xw2[d] + sum_e wt[e]*xw2[src[e]]
// EIGHT nodes per wave: 8 lanes x u32x4 (16B) = 128B row. WRITE-ONLY out.
__global__ __launch_bounds__(256)
void gather64b(const int* __restrict__ offs, const u32x2* __restrict__ recS,
               const float* __restrict__ dinv, const u32x4* __restrict__ xw4,
               const float* __restrict__ b2, float* __restrict__ out) {
    const int t    = blockIdx.x * 256 + threadIdx.x;
    const int d    = t >> 3;
    const int lane = t & 7;
    if (d >= NND) return;
    const int beg = offs[d], end = offs[d + 1];
    const float dd = dinv[d];
    const float d2 = dd * dd;
    const u32x4 s = xw4[(size_t)d * 8 + lane];
    const float4 bl = *(const float4*)&b2[lane * 8];
    const float4 bh = *(const float4*)&b2[lane * 8 + 4];
    float a0 = fmaf(d2, b2f((u16)s.x), bl.x), a1 = fmaf(d2, b2f((u16)(s.x >> 16)), bl.y);
    float a2 = fmaf(d2, b2f((u16)s.y), bl.z), a3 = fmaf(d2, b2f((u16)(s.y >> 16)), bl.w);
    float a4 = fmaf(d2, b2f((u16)s.z), bh.x), a5 = fmaf(d2, b2f((u16)(s.z >> 16)), bh.y);
    float a6 = fmaf(d2, b2f((u16)s.w), bh.z), a7 = fmaf(d2, b2f((u16)(s.w >> 16)), bh.w);
    for (int e = beg; e < end; e += 8) {
        u32x2 r[8]; float wi[8]; u32x4 vi[8];
        #pragma unroll
        for (int j = 0; j < 8; ++j) {
            const int ee = e + j;
            r[j] = __builtin_nontemporal_load(&recS[(ee < end) ? ee : (end - 1)]);
        }
        #pragma unroll
        for (int j = 0; j < 8; ++j) {
            wi[j] = (e + j < end) ? __uint_as_float(r[j].y) : 0.0f;
            vi[j] = xw4[(size_t)r[j].x * 8 + lane];
        }
        #pragma unroll
        for (int j = 0; j < 8; ++j) {
            a0 = fmaf(wi[j], b2f((u16)vi[j].x), a0);
            a1 = fmaf(wi[j], b2f((u16)(vi[j].x >> 16)), a1);
            a2 = fmaf(wi[j], b2f((u16)vi[j].y), a2);
            a3 = fmaf(wi[j], b2f((u16)(vi[j].y >> 16)), a3);
            a4 = fmaf(wi[j], b2f((u16)vi[j].z), a4);
            a5 = fmaf(wi[j], b2f((u16)(vi[j].z >> 16)), a5);
            a6 = fmaf(wi[j], b2f((u16)vi[j].w), a6);
            a7 = fmaf(wi[j], b2f((u16)(vi[j].w >> 16)), a7);
        }
    }
    float* p = &out[(size_t)d * 64 + lane * 8];
    *(float4*)(p + 0) = make_float4(a0, a1, a2, a3);
    *(float4*)(p + 4) = make_float4(a4, a5, a6, a7);
}

// ---------------------------------------------------------------------------
// FUSED two-layer GEMM v2 — barrier-minimal:
// Operands A(=zb, L3-hot), W1t/W2t (L2-hot) are read DIRECTLY from global as
// 16B/lane b128 fragments — no LDS staging, no vmcnt-drain barriers. Only the
// 64x256 bf16 h-tile lives in LDS (33 KB -> 4 blocks/CU), with ONE barrier
// between the relu-epilogue and phase 2. All loops fully unrolled for MLP.
//   phase 1: acc = z[64x128] @ W1t^T -> Hs = relu(acc + b1)
//   phase 2: xw2[64x64] = Hs @ W2t^T (a2 fragments hoisted, 32 indep loads)
// ---------------------------------------------------------------------------
__global__ __launch_bounds__(256)
void gemm_fused(const u16* __restrict__ A, const u16* __restrict__ W1t,
                const u16* __restrict__ W2t, const float* __restrict__ b1,
                u16* __restrict__ O, int M)
{
    __shared__ __align__(16) u16 Hs[64 * 264];    // 33 KB
    const int lane = threadIdx.x & 63;
    const int wid  = threadIdx.x >> 6;
    const int row0 = blockIdx.x * 64;
    const int wcol0 = wid * 64;                   // phase-1 col slab
    const int ch = (lane >> 4);                   // k-chunk 0..3 (8 elems)
    const int rb = ch * 4;
    const int cl = lane & 15;

    // ---- phase 1: 64x256 = z[64x128] @ W1t^T, operands from global ----
    f32x4 acc[4][4];
    #pragma unroll
    for (int i = 0; i < 4; ++i)
        #pragma unroll
        for (int j = 0; j < 4; ++j) acc[i][j] = (f32x4){0.f, 0.f, 0.f, 0.f};

    #pragma unroll
    for (int kt = 0; kt < 128; kt += 32) {
        bf16x8 af[4], bfr[4];
        #pragma unroll
        for (int mi = 0; mi < 4; ++mi) {
            int row = row0 + mi * 16 + cl;
            if (row >= M) row = M - 1;
            af[mi] = *(const bf16x8*)&A[(size_t)row * 128 + kt + ch * 8];
        }
        #pragma unroll
        for (int ni = 0; ni < 4; ++ni)
            bfr[ni] = *(const bf16x8*)&W1t[(size_t)(wcol0 + ni * 16 + cl) * 128 + kt + ch * 8];
        #pragma unroll
        for (int mi = 0; mi < 4; ++mi)
            #pragma unroll
            for (int ni = 0; ni < 4; ++ni)
                acc[mi][ni] = __builtin_amdgcn_mfma_f32_16x16x32_bf16(
                    af[mi], bfr[ni], acc[mi][ni], 0, 0, 0);
    }

    // epilogue -> Hs (relu + b1), bf16
    float bo[4];
    #pragma unroll
    for (int ni = 0; ni < 4; ++ni) bo[ni] = b1[wcol0 + ni * 16 + cl];
    #pragma unroll
    for (int mi = 0; mi < 4; ++mi)
        #pragma unroll
        for (int r = 0; r < 4; ++r) {
            const int row = mi * 16 + rb + r;
            #pragma unroll
            for (int ni = 0; ni < 4; ++ni)
                Hs[row * 264 + wcol0 + ni * 16 + cl] =
                    f2b(fmaxf(acc[mi][ni][r] + bo[ni], 0.f));
        }
    __syncthreads();                               // the ONE barrier

    // ---- phase 2: 64x64 = Hs[64x256] @ W2t^T, wave owns 16 rows ----
    bf16x8 a2[8];
    #pragma unroll
    for (int k8 = 0; k8 < 8; ++k8)                 // hoist all Hs fragments
        a2[k8] = *(const bf16x8*)&Hs[(wid * 16 + cl) * 264 + k8 * 32 + ch * 8];

    f32x4 acc2[4];
    #pragma unroll
    for (int ni = 0; ni < 4; ++ni) acc2[ni] = (f32x4){0.f, 0.f, 0.f, 0.f};
    #pragma unroll
    for (int k8 = 0; k8 < 8; ++k8) {
        #pragma unroll
        for (int ni = 0; ni < 4; ++ni) {
            const bf16x8 b2v = *(const bf16x8*)&W2t[(size_t)(ni * 16 + cl) * 256 + k8 * 32 + ch * 8];
            acc2[ni] = __builtin_amdgcn_mfma_f32_16x16x32_bf16(a2[k8], b2v, acc2[ni], 0, 0, 0);
        }
    }
    #pragma unroll
    for (int ni = 0; ni < 4; ++ni)
        #pragma unroll
        for (int r = 0; r < 4; ++r) {
            const int row = row0 + wid * 16 + rb + r;
            if (row < M) O[(size_t)row * 64 + ni * 16 + cl] = f2b(acc2[ni][r]);
        }
}

// ---------------------------------------------------------------------------
extern "C" void kernel_launch(void* const* d_in, const int* in_sizes, int n_in,
                              void* d_out, int out_size, void* d_ws, size_t ws_size,
                              hipStream_t stream)
{
    const float* x  = (const float*)d_in[0];
    const int*   ei = (const int*)d_in[1];   // [2, E]: src row then dst row
    const float* W1 = (const float*)d_in[2];
    const float* b1 = (const float*)d_in[3];
    const float* W2 = (const float*)d_in[4];
    const float* b2 = (const float*)d_in[5];
    float* out = (float*)d_out;

    // workspace layout (bytes, all 128-aligned):
    char* ws = (char*)d_ws;
    float* dinv   = (float*)(ws + 0);          //    400,000 -> 400,128
    int*   offs   = (int*)  (ws + 400128);     //    400,004 -> 800,256
    int*   bsum   = (int*)  (ws + 800256);     //        512 -> 800,768
    int*   cntmat = (int*)  (ws + 800768);     // 10,000,000 -> 10,800,768 (25 x NND)
    u32x2* recS   = (u32x2*)(ws + 10800768);   //  5,120,000 -> 15,920,768 (packed src+wt)
    u32*   xb     = (u32*)  (ws + 15920768);   // 25,600,000 -> 41,520,768  (x bf16)
    u32*   zb     = (u32*)  (ws + 41520768);   // 25,600,000 -> 67,120,768  (Ax bf16)
    u16*   W1t    = (u16*)  (ws + 67120768);   //     65,536 -> 67,186,304
    u16*   W2t    = (u16*)  (ws + 67186304);   //     32,768 -> 67,219,072
    u16*   xwb    = (u16*)  (ws + 67219072);   // 12,800,000 -> 80,019,072 (xw2 bf16)

    // ---- pass A (LDS histogram, no global atomics) || cvt x || cvt W ----
    pre_all<<<PRE_N, 1024, 0, stream>>>(ei, cntmat, x, xb, W1, W2, W1t, W2t);

    // ---- chunk-base scan + dinv + offs scan ----
    scanA_dinv<<<NSCAN_B, 256, 0, stream>>>(cntmat, offs, bsum, dinv);
    scanC2<<<(NND + 255) / 256, 256, 0, stream>>>(offs, bsum);

    // ---- LDS-cursor fill (no global atomics, 16 waves/block) ----
    fill_lds<<<HISTB, 1024, 0, stream>>>(ei, cntmat, offs, dinv, recS);

    // ---- layer 1 gather: z = A~ x (bf16, 4 nodes/wave) ----
    gather128b<<<(NND * 16 + 255) / 256, 256, 0, stream>>>(
        offs, recS, dinv, (const u32x4*)xb, (u32x4*)zb);

    // ---- fused: h=relu(z@W1+b1) in LDS, xw2 = h@W2 (no h tensor) ----
    gemm_fused<<<(NND + 63) / 64, 256, 0, stream>>>(
        (const u16*)zb, W1t, W2t, b1, xwb, NND);

    // ---- layer 2 gather: out = b2 + dinv^2*xw2 + edges (8 nodes/wave) ----
    gather64b<<<(NND * 8 + 255) / 256, 256, 0, stream>>>(
        offs, recS, dinv, (const u32x4*)xwb, b2, out);
}

// Round 18
// 148.558 us; speedup vs baseline: 1.0822x; 1.0822x over previous
//
#include <hip/hip_runtime.h>
#include <cstdint>
#include <cstddef>

#define NND 100000
#define NED 640000
#define NSCAN_B 98          // ceil(NND/1024)
#define NPART 8             // dst-space partitions
#define PSZ 12500           // NND / NPART  (LDS histogram bins per partition)
#define KCH 25              // edge chunks
#define CHE 25600           // edges per chunk (25600*25 = 640,000 exact)
#define HISTB (NPART * KCH)             // 200 hist/fill blocks
#define CVTX_B 782          // cvt_x blocks: ceil(3,200,000 float4 / 4096)
#define CVTW_B 48           // cvt_w blocks: 49,152 / 1024 exact
#define PRE_N (HISTB + CVTX_B + CVTW_B) // 1030 pre_all blocks (1024 thr)

typedef unsigned int u32;
typedef unsigned short u16;
typedef __attribute__((ext_vector_type(8))) short bf16x8;
typedef __attribute__((ext_vector_type(4))) float f32x4;
typedef __attribute__((ext_vector_type(2))) u32 u32x2;
typedef __attribute__((ext_vector_type(4))) u32 u32x4;

// ---------------------------------------------------------------------------
// helpers: fp32 <-> bf16 (RNE), async global->LDS 16B
// ---------------------------------------------------------------------------
__device__ __forceinline__ u16 f2b(float f) {
    u32 u = __float_as_uint(f);
    return (u16)((u + 0x7fffu + ((u >> 16) & 1u)) >> 16);
}
__device__ __forceinline__ float b2f(u16 b) {
    return __uint_as_float(((u32)b) << 16);
}
__device__ __forceinline__ u32 pack2(float a, float b) {
    return (u32)f2b(a) | ((u32)f2b(b) << 16);
}
__device__ __forceinline__ void gload16(u16* lds, const u16* g) {
    __builtin_amdgcn_global_load_lds(
        (const __attribute__((address_space(1))) u32*)g,
        (__attribute__((address_space(3))) u32*)lds,
        16, 0, 0);
}

// ---------------------------------------------------------------------------
// pre_all — ZERO global atomics, 1024-thread blocks:
//   blocks [0, 200):      pass A — LDS count histogram per (partition, chunk)
//   blocks [200, 982):    cvt x->bf16
//   blocks [982, 1030):   cvt W1,W2 -> transposed bf16
// ---------------------------------------------------------------------------
__global__ __launch_bounds__(1024)
void pre_all(const int* __restrict__ ei, int* __restrict__ cntmat,
             const float* __restrict__ x, u32* __restrict__ xb,
             const float* __restrict__ W1, const float* __restrict__ W2,
             u16* __restrict__ W1t, u16* __restrict__ W2t) {
    __shared__ int hist[PSZ];
    const int b = blockIdx.x;
    const int t = threadIdx.x;
    if (b < HISTB) {
        const int part = b & 7, chunk = b >> 3;
        const int lo = part * PSZ;
        for (int i = t; i < PSZ; i += 1024) hist[i] = 0;
        __syncthreads();
        const int base = chunk * CHE;
        #pragma unroll
        for (int it = 0; it < 7; ++it) {
            const int off = (it * 1024 + t) * 4;
            if (off < CHE) {
                const int4 d = *(const int4*)&ei[NED + base + off];
                const int dv[4] = {d.x, d.y, d.z, d.w};
                #pragma unroll
                for (int j = 0; j < 4; ++j) {
                    const unsigned u = (unsigned)(dv[j] - lo);
                    if (u < PSZ) atomicAdd(&hist[u], 1);
                }
            }
        }
        __syncthreads();
        for (int i = t; i < PSZ; i += 1024)
            cntmat[chunk * NND + lo + i] = hist[i];
    } else if (b < HISTB + CVTX_B) {
        const int cb = b - HISTB;
        const float4* __restrict__ x4 = (const float4*)x;
        #pragma unroll
        for (int j = 0; j < 4; ++j) {
            const int f4 = cb * 4096 + j * 1024 + t;      // float4 index
            if (f4 < 3200000) {
                const float4 v = x4[f4];
                xb[(size_t)f4 * 2 + 0] = pack2(v.x, v.y);
                xb[(size_t)f4 * 2 + 1] = pack2(v.z, v.w);
            }
        }
    } else {
        const int i = (b - (HISTB + CVTX_B)) * 1024 + t;  // < 49,152 exact
        if (i < 128 * 256) {
            const int k = i >> 8, n = i & 255;
            W1t[n * 128 + k] = f2b(W1[i]);
        } else {
            const int j = i - 128 * 256;                  // j < 256*64
            const int k = j >> 6, n = j & 63;
            W2t[n * 256 + k] = f2b(W2[j]);
        }
    }
}

// ---------------------------------------------------------------------------
// scanA_dinv: per bin, (1) scan cntmat over the 25 chunks IN PLACE, (2)
// dinv = rsqrt(1+deg), (3) per-1024 exclusive scan of deg -> offs + bsum.
// ---------------------------------------------------------------------------
__global__ __launch_bounds__(256)
void scanA_dinv(int* __restrict__ cntmat, int* __restrict__ offs,
                int* __restrict__ bsum, float* __restrict__ dinv) {
    __shared__ int s[256];
    const int t = threadIdx.x;
    const int base = blockIdx.x * 1024 + t * 4;
    int t0 = 0, t1 = 0, t2 = 0, t3 = 0;
    if (base < NND) {
        #pragma unroll 5
        for (int c = 0; c < KCH; ++c) {
            int4* p = (int4*)&cntmat[c * NND + base];
            const int4 v = *p;
            *p = make_int4(t0, t1, t2, t3);               // exclusive base
            t0 += v.x; t1 += v.y; t2 += v.z; t3 += v.w;
        }
        dinv[base + 0] = rsqrtf(1.0f + (float)t0);
        dinv[base + 1] = rsqrtf(1.0f + (float)t1);
        dinv[base + 2] = rsqrtf(1.0f + (float)t2);
        dinv[base + 3] = rsqrtf(1.0f + (float)t3);
    }
    const int local = t0 + t1 + t2 + t3;
    s[t] = local;
    __syncthreads();
    for (int off = 1; off < 256; off <<= 1) {
        int v = (t >= off) ? s[t - off] : 0;
        __syncthreads();
        s[t] += v;
        __syncthreads();
    }
    const int excl = s[t] - local;
    if (t == 255) bsum[blockIdx.x] = s[255];
    if (base < NND) {
        offs[base + 0] = excl;
        offs[base + 1] = excl + t0;
        offs[base + 2] = excl + t0 + t1;
        offs[base + 3] = excl + t0 + t1 + t2;
    }
}

// scanC2: each block redundantly prefixes the 98 block sums, then applies.
__global__ __launch_bounds__(256)
void scanC2(int* __restrict__ offs, const int* __restrict__ bsum) {
    __shared__ int pref[NSCAN_B];
    if (threadIdx.x < NSCAN_B) pref[threadIdx.x] = bsum[threadIdx.x];
    __syncthreads();
    if (threadIdx.x == 0) {
        int run = 0;
        #pragma unroll 1
        for (int b = 0; b < NSCAN_B; ++b) { int v = pref[b]; pref[b] = run; run += v; }
    }
    __syncthreads();
    const int i = blockIdx.x * 256 + threadIdx.x;
    if (i < NND) offs[i] += pref[i >> 10];
    if (i == 0) offs[NND] = NED;
}

// ---------------------------------------------------------------------------
// fill_lds: LDS-cursor CSR fill, zero global atomics, 1024-thread blocks.
// ---------------------------------------------------------------------------
__global__ __launch_bounds__(1024)
void fill_lds(const int* __restrict__ ei, const int* __restrict__ cntmat,
              const int* __restrict__ offs, const float* __restrict__ dinv,
              u32x2* __restrict__ recS) {
    __shared__ int cur[PSZ];
    const int t = threadIdx.x;
    const int part = blockIdx.x & 7, chunk = blockIdx.x >> 3;
    const int lo = part * PSZ;
    for (int i = t; i < PSZ; i += 1024)
        cur[i] = offs[lo + i] + cntmat[chunk * NND + lo + i];
    __syncthreads();
    const int base = chunk * CHE;
    #pragma unroll
    for (int it = 0; it < 7; ++it) {
        const int off = (it * 1024 + t) * 4;
        if (off < CHE) {
            const int e = base + off;
            const int4 s4 = *(const int4*)&ei[e];
            const int4 d4 = *(const int4*)&ei[NED + e];
            const int sv[4] = {s4.x, s4.y, s4.z, s4.w};
            const int dv[4] = {d4.x, d4.y, d4.z, d4.w};
            #pragma unroll
            for (int j = 0; j < 4; ++j) {
                const unsigned u = (unsigned)(dv[j] - lo);
                if (u < PSZ) {
                    const float wt = dinv[sv[j]] * dinv[dv[j]];
                    const int pos = atomicAdd(&cur[u], 1);
                    u32x2 rec = {(u32)sv[j], __float_as_uint(wt)};
                    recS[pos] = rec;
                }
            }
        }
    }
}

// ---------------------------------------------------------------------------
// CSR gather (bf16), 8-wide predicated edge groups, packed edge records.
// FOUR nodes per wave: 16 lanes x u32x4 (16B) = 256B row.
// z[d] = dinv[d]^2*x[d] + sum_e wt[e]*x[src[e]]
// ---------------------------------------------------------------------------
__global__ __launch_bounds__(256)
void gather128b(const int* __restrict__ offs, const u32x2* __restrict__ recS,
                const float* __restrict__ dinv,
                const u32x4* __restrict__ xb4, u32x4* __restrict__ zb4) {
    const int t    = blockIdx.x * 256 + threadIdx.x;
    const int d    = t >> 4;
    const int lane = t & 15;
    if (d >= NND) return;
    const int beg = offs[d], end = offs[d + 1];
    const float dd = dinv[d];
    const u32x4 s = xb4[(size_t)d * 16 + lane];
    const float d2 = dd * dd;
    float a0 = b2f((u16)s.x) * d2, a1 = b2f((u16)(s.x >> 16)) * d2;
    float a2 = b2f((u16)s.y) * d2, a3 = b2f((u16)(s.y >> 16)) * d2;
    float a4 = b2f((u16)s.z) * d2, a5 = b2f((u16)(s.z >> 16)) * d2;
    float a6 = b2f((u16)s.w) * d2, a7 = b2f((u16)(s.w >> 16)) * d2;
    for (int e = beg; e < end; e += 8) {
        u32x2 r[8]; float wi[8]; u32x4 vi[8];
        #pragma unroll
        for (int j = 0; j < 8; ++j) {
            const int ee = e + j;
            r[j] = __builtin_nontemporal_load(&recS[(ee < end) ? ee : (end - 1)]);
        }
        #pragma unroll
        for (int j = 0; j < 8; ++j) {
            wi[j] = (e + j < end) ? __uint_as_float(r[j].y) : 0.0f;
            vi[j] = xb4[(size_t)r[j].x * 16 + lane];
        }
        #pragma unroll
        for (int j = 0; j < 8; ++j) {
            a0 = fmaf(wi[j], b2f((u16)vi[j].x), a0);
            a1 = fmaf(wi[j], b2f((u16)(vi[j].x >> 16)), a1);
            a2 = fmaf(wi[j], b2f((u16)vi[j].y), a2);
            a3 = fmaf(wi[j], b2f((u16)(vi[j].y >> 16)), a3);
            a4 = fmaf(wi[j], b2f((u16)vi[j].z), a4);
            a5 = fmaf(wi[j], b2f((u16)(vi[j].z >> 16)), a5);
            a6 = fmaf(wi[j], b2f((u16)vi[j].w), a6);
            a7 = fmaf(wi[j], b2f((u16)(vi[j].w >> 16)), a7);
        }
    }
    u32x4 o = {pack2(a0, a1), pack2(a2, a3), pack2(a4, a5), pack2(a6, a7)};
    zb4[(size_t)d * 16 + lane] = o;
}

// out[d] = b2 + dinv[d]^2*xw2[d] + sum_e wt[e]*xw2[src[e]]
// EIGHT nodes per wave: 8 lanes x u32x4 (16B) = 128B row. WRITE-ONLY out.
__global__ __launch_bounds__(256)
void gather64b(const int* __restrict__ offs, const u32x2* __restrict__ recS,
               const float* __restrict__ dinv, const u32x4* __restrict__ xw4,
               const float* __restrict__ b2, float* __restrict__ out) {
    const int t    = blockIdx.x * 256 + threadIdx.x;
    const int d    = t >> 3;
    const int lane = t & 7;
    if (d >= NND) return;
    const int beg = offs[d], end = offs[d + 1];
    const float dd = dinv[d];
    const float d2 = dd * dd;
    const u32x4 s = xw4[(size_t)d * 8 + lane];
    const float4 bl = *(const float4*)&b2[lane * 8];
    const float4 bh = *(const float4*)&b2[lane * 8 + 4];
    float a0 = fmaf(d2, b2f((u16)s.x), bl.x), a1 = fmaf(d2, b2f((u16)(s.x >> 16)), bl.y);
    float a2 = fmaf(d2, b2f((u16)s.y), bl.z), a3 = fmaf(d2, b2f((u16)(s.y >> 16)), bl.w);
    float a4 = fmaf(d2, b2f((u16)s.z), bh.x), a5 = fmaf(d2, b2f((u16)(s.z >> 16)), bh.y);
    float a6 = fmaf(d2, b2f((u16)s.w), bh.z), a7 = fmaf(d2, b2f((u16)(s.w >> 16)), bh.w);
    for (int e = beg; e < end; e += 8) {
        u32x2 r[8]; float wi[8]; u32x4 vi[8];
        #pragma unroll
        for (int j = 0; j < 8; ++j) {
            const int ee = e + j;
            r[j] = __builtin_nontemporal_load(&recS[(ee < end) ? ee : (end - 1)]);
        }
        #pragma unroll
        for (int j = 0; j < 8; ++j) {
            wi[j] = (e + j < end) ? __uint_as_float(r[j].y) : 0.0f;
            vi[j] = xw4[(size_t)r[j].x * 8 + lane];
        }
        #pragma unroll
        for (int j = 0; j < 8; ++j) {
            a0 = fmaf(wi[j], b2f((u16)vi[j].x), a0);
            a1 = fmaf(wi[j], b2f((u16)(vi[j].x >> 16)), a1);
            a2 = fmaf(wi[j], b2f((u16)vi[j].y), a2);
            a3 = fmaf(wi[j], b2f((u16)(vi[j].y >> 16)), a3);
            a4 = fmaf(wi[j], b2f((u16)vi[j].z), a4);
            a5 = fmaf(wi[j], b2f((u16)(vi[j].z >> 16)), a5);
            a6 = fmaf(wi[j], b2f((u16)vi[j].w), a6);
            a7 = fmaf(wi[j], b2f((u16)(vi[j].w >> 16)), a7);
        }
    }
    float* p = &out[(size_t)d * 64 + lane * 8];
    *(float4*)(p + 0) = make_float4(a0, a1, a2, a3);
    *(float4*)(p + 4) = make_float4(a4, a5, a6, a7);
}

// ---------------------------------------------------------------------------
// FUSED two-layer GEMM v3 — r16's LDS-staged structure with an LDS UNION:
// As/Bs (20KB, phase-1 staging) overlay the front of Hs (33KB) — they are
// dead after the K-loop's final barrier, and Hs is written only after it.
// Total LDS 33KB -> 4 blocks/CU (was 53KB -> 2), doubling the co-resident
// blocks available to hide the per-K-step vmcnt-drain barriers.
//   phase 1: Hs = relu(z@W1 + b1)   (64x256 bf16 in LDS — no h tensor)
//   phase 2: xw2 = Hs@W2            (64x64 bf16, W2t from L2)
// ---------------------------------------------------------------------------
__global__ __launch_bounds__(256)
void gemm_fused(const u16* __restrict__ A, const u16* __restrict__ W1t,
                const u16* __restrict__ W2t, const float* __restrict__ b1,
                u16* __restrict__ O, int M)
{
    __shared__ __align__(16) u16 lds[64 * 264];   // 33 KB arena
    u16* As = lds;                                // [64*32]   phase-1 only
    u16* Bs = lds + 2048;                         // [256*32]  phase-1 only
    u16* Hs = lds;                                // [64*264]  after K-loop
    const int tid  = threadIdx.x;
    const int lane = tid & 63;
    const int wid  = tid >> 6;
    const int row0 = blockIdx.x * 64;
    const int wcol0 = wid * 64;
    const int lr = lane >> 2;          // row within 16-row load chunk
    const int lk = (lane & 3) * 8;     // k offset (16B granule)
    const int rb = (lane >> 4) * 4;
    const int cl = lane & 15;

    // ---- phase 1: 64x256 = z[64x128] @ W1t^T ----
    f32x4 acc[4][4];
    #pragma unroll
    for (int i = 0; i < 4; ++i)
        #pragma unroll
        for (int j = 0; j < 4; ++j) acc[i][j] = (f32x4){0.f, 0.f, 0.f, 0.f};

    for (int kt = 0; kt < 128; kt += 32) {
        {   // A: 4 waves cover 64 rows (16 each)
            const int r  = wid * 16 + lr;
            const int rg = (row0 + r < M) ? (row0 + r) : (M - 1);
            gload16(&As[wid * 512], &A[(size_t)rg * 128 + kt + lk]);
        }
        #pragma unroll
        for (int j = 0; j < 4; ++j) {   // B: 16 chunks cover 256 W1t rows
            const int li = wid * 4 + j;
            const int n  = li * 16 + lr;
            gload16(&Bs[li * 512], &W1t[(size_t)n * 128 + kt + lk]);
        }
        __syncthreads();
        bf16x8 af[4], bfr[4];
        #pragma unroll
        for (int mi = 0; mi < 4; ++mi)
            af[mi] = *(const bf16x8*)&As[(mi * 16 + cl) * 32 + (lane >> 4) * 8];
        #pragma unroll
        for (int ni = 0; ni < 4; ++ni)
            bfr[ni] = *(const bf16x8*)&Bs[(wcol0 + ni * 16 + cl) * 32 + (lane >> 4) * 8];
        #pragma unroll
        for (int mi = 0; mi < 4; ++mi)
            #pragma unroll
            for (int ni = 0; ni < 4; ++ni)
                acc[mi][ni] = __builtin_amdgcn_mfma_f32_16x16x32_bf16(
                    af[mi], bfr[ni], acc[mi][ni], 0, 0, 0);
        __syncthreads();                // last iter: As/Bs dead after this
    }

    // epilogue -> Hs (relu + b1), bf16   (overlays the dead As/Bs region)
    float bo[4];
    #pragma unroll
    for (int ni = 0; ni < 4; ++ni) bo[ni] = b1[wcol0 + ni * 16 + cl];
    #pragma unroll
    for (int mi = 0; mi < 4; ++mi)
        #pragma unroll
        for (int r = 0; r < 4; ++r) {
            const int row = mi * 16 + rb + r;
            #pragma unroll
            for (int ni = 0; ni < 4; ++ni)
                Hs[row * 264 + wcol0 + ni * 16 + cl] =
                    f2b(fmaxf(acc[mi][ni][r] + bo[ni], 0.f));
        }
    __syncthreads();

    // ---- phase 2: 64x64 = Hs[64x256] @ W2t^T, wave owns 16 rows ----
    bf16x8 a2[8];
    #pragma unroll
    for (int k8 = 0; k8 < 8; ++k8)
        a2[k8] = *(const bf16x8*)&Hs[(wid * 16 + cl) * 264 + k8 * 32 + (lane >> 4) * 8];

    f32x4 acc2[4];
    #pragma unroll
    for (int ni = 0; ni < 4; ++ni) acc2[ni] = (f32x4){0.f, 0.f, 0.f, 0.f};
    #pragma unroll
    for (int k8 = 0; k8 < 8; ++k8) {
        #pragma unroll
        for (int ni = 0; ni < 4; ++ni) {
            const bf16x8 b2v = *(const bf16x8*)&W2t[(size_t)(ni * 16 + cl) * 256 + k8 * 32 + (lane >> 4) * 8];
            acc2[ni] = __builtin_amdgcn_mfma_f32_16x16x32_bf16(a2[k8], b2v, acc2[ni], 0, 0, 0);
        }
    }
    #pragma unroll
    for (int ni = 0; ni < 4; ++ni)
        #pragma unroll
        for (int r = 0; r < 4; ++r) {
            const int row = row0 + wid * 16 + rb + r;
            if (row < M) O[(size_t)row * 64 + ni * 16 + cl] = f2b(acc2[ni][r]);
        }
}

// ---------------------------------------------------------------------------
extern "C" void kernel_launch(void* const* d_in, const int* in_sizes, int n_in,
                              void* d_out, int out_size, void* d_ws, size_t ws_size,
                              hipStream_t stream)
{
    const float* x  = (const float*)d_in[0];
    const int*   ei = (const int*)d_in[1];   // [2, E]: src row then dst row
    const float* W1 = (const float*)d_in[2];
    const float* b1 = (const float*)d_in[3];
    const float* W2 = (const float*)d_in[4];
    const float* b2 = (const float*)d_in[5];
    float* out = (float*)d_out;

    // workspace layout (bytes, all 128-aligned):
    char* ws = (char*)d_ws;
    float* dinv   = (float*)(ws + 0);          //    400,000 -> 400,128
    int*   offs   = (int*)  (ws + 400128);     //    400,004 -> 800,256
    int*   bsum   = (int*)  (ws + 800256);     //        512 -> 800,768
    int*   cntmat = (int*)  (ws + 800768);     // 10,000,000 -> 10,800,768 (25 x NND)
    u32x2* recS   = (u32x2*)(ws + 10800768);   //  5,120,000 -> 15,920,768 (packed src+wt)
    u32*   xb     = (u32*)  (ws + 15920768);   // 25,600,000 -> 41,520,768  (x bf16)
    u32*   zb     = (u32*)  (ws + 41520768);   // 25,600,000 -> 67,120,768  (Ax bf16)
    u16*   W1t    = (u16*)  (ws + 67120768);   //     65,536 -> 67,186,304
    u16*   W2t    = (u16*)  (ws + 67186304);   //     32,768 -> 67,219,072
    u16*   xwb    = (u16*)  (ws + 67219072);   // 12,800,000 -> 80,019,072 (xw2 bf16)

    // ---- pass A (LDS histogram, no global atomics) || cvt x || cvt W ----
    pre_all<<<PRE_N, 1024, 0, stream>>>(ei, cntmat, x, xb, W1, W2, W1t, W2t);

    // ---- chunk-base scan + dinv + offs scan ----
    scanA_dinv<<<NSCAN_B, 256, 0, stream>>>(cntmat, offs, bsum, dinv);
    scanC2<<<(NND + 255) / 256, 256, 0, stream>>>(offs, bsum);

    // ---- LDS-cursor fill (no global atomics, 16 waves/block) ----
    fill_lds<<<HISTB, 1024, 0, stream>>>(ei, cntmat, offs, dinv, recS);

    // ---- layer 1 gather: z = A~ x (bf16, 4 nodes/wave) ----
    gather128b<<<(NND * 16 + 255) / 256, 256, 0, stream>>>(
        offs, recS, dinv, (const u32x4*)xb, (u32x4*)zb);

    // ---- fused: h=relu(z@W1+b1) in LDS, xw2 = h@W2 (no h tensor) ----
    gemm_fused<<<(NND + 63) / 64, 256, 0, stream>>>(
        (const u16*)zb, W1t, W2t, b1, xwb, NND);

    // ---- layer 2 gather: out = b2 + dinv^2*xw2 + edges (8 nodes/wave) ----
    gather64b<<<(NND * 8 + 255) / 256, 256, 0, stream>>>(
        offs, recS, dinv, (const u32x4*)xwb, b2, out);
}